// Round 22
// baseline (3355.978 us; speedup 1.0000x reference)
//
#include <hip/hip_runtime.h>

// LSTM H=512, B=256, T=256, D_IN=10, C=10. fp32 in/out.
// R22: 8-wave restructure. 256 WGs = 64 row-groups x 4 col-groups; WG = 32
// stacked rows x 64 cols, 512 threads (8 waves = 2 row x 4 col positions),
// each lane ONE cell. Full 64-col panel in LDS (no A/B phase serialization -
// column quarters run concurrently across waves; 2 waves/SIMD overlap stalls).
// 3 barriers/step, single flag set (poll = 64 parallel lanes). LDS 139.8KB ->
// 1 WG/CU. Fabric primitives identical to R18/R21 (agent atomics, 64B flag
// lines, bounded s_sleep poll, LDS-bounce coalesced h store).
// WAR induction: WG stores h(t) only after poll(t) confirms all 64 consumers
// posted flag(t) (= completed step t-1 incl. staging reads of that buffer).

#define Hdim 512
#define Bdim 256
#define Tdim 256
#define Kpad 544          // 512 (h) + 32 (x: 10 real + 22 zero)
#define LROW 548          // weight LDS row stride (shorts): 274w%32=18 -> clean
#define PROW 536          // panel LDS col stride (shorts): 268w%32=12 -> 2-way reads
#define LDS_BYTES ((32 * LROW * 2 + 64 * PROW + 512) * 2)   // 139,776 B -> 1 WG/CU

typedef __bf16 bf16x8 __attribute__((ext_vector_type(8)));
typedef float f32x4 __attribute__((ext_vector_type(4)));
typedef unsigned long long u64;

__device__ __forceinline__ unsigned short f2bf(float f) {
    union { float f; unsigned u; } x; x.f = f;
    unsigned r = x.u + 0x7FFFu + ((x.u >> 16) & 1u);
    return (unsigned short)(r >> 16);
}
__device__ __forceinline__ float bf2f(unsigned short h) {
    union { unsigned u; float f; } x; x.u = ((unsigned)h) << 16;
    return x.f;
}
__device__ __forceinline__ bf16x8 ld8(const unsigned short* p) {
    return *reinterpret_cast<const bf16x8*>(p);
}
__device__ __forceinline__ u64 ldA(const u64* p) {   // coherent 8B load (L3)
    return __hip_atomic_load(p, __ATOMIC_RELAXED, __HIP_MEMORY_SCOPE_AGENT);
}
// write-through 4B store (agent scope -> lands at coherence point)
__device__ __forceinline__ void stH32(unsigned* p, unsigned v) {
    __hip_atomic_store(p, v, __ATOMIC_RELAXED, __HIP_MEMORY_SCOPE_AGENT);
}
__device__ __forceinline__ f32x4 mfma16(bf16x8 a, bf16x8 b, f32x4 c) {
    return __builtin_amdgcn_mfma_f32_16x16x32_bf16(a, b, c, 0, 0, 0);
}
__device__ __forceinline__ bf16x8 pack2(u64 a, u64 b) {
    union { u64 q[2]; bf16x8 v; } u; u.q[0] = a; u.q[1] = b; return u.v;
}
__device__ __forceinline__ float sigm(float x) { return 1.f / (1.f + __expf(-x)); }
__device__ __forceinline__ float tanh_fast(float x) {
    return 2.f / (1.f + __expf(-2.f * x)) - 1.f;
}
// 64-lane parallel poll of the col-group's 64 flag lines, bounded, hot first try
__device__ __forceinline__ void poll64(const unsigned* pollp, unsigned tgt) {
    unsigned v = __hip_atomic_load(pollp, __ATOMIC_RELAXED, __HIP_MEMORY_SCOPE_AGENT);
    bool ok = (v >= tgt);
    int guard = 1 << 16;   // bounded: pathological case -> no hang
    while (!ok && --guard) {
        __builtin_amdgcn_s_sleep(1);
        v = __hip_atomic_load(pollp, __ATOMIC_RELAXED, __HIP_MEMORY_SCOPE_AGENT);
        ok = (v >= tgt);
    }
}

// ---------- prep: stacked gate weights -> bf16 hi/lo, row = 4*i + gate ----------
__global__ void k_prep_w(const float* __restrict__ w_gh, const float* __restrict__ w_ih,
                         const float* __restrict__ w_fh, const float* __restrict__ w_oh,
                         const float* __restrict__ w_gx, const float* __restrict__ w_ix,
                         const float* __restrict__ w_fx, const float* __restrict__ w_ox,
                         unsigned short* __restrict__ Whi, unsigned short* __restrict__ Wlo) {
    int idx = blockIdx.x * 256 + threadIdx.x;
    if (idx >= 2048 * Kpad) return;
    int rw = idx / Kpad;
    int k  = idx % Kpad;
    int gate = rw & 3;
    int i = rw >> 2;
    float v = 0.f;
    if (k < 512) {
        const float* wh = (gate == 0) ? w_gh : (gate == 1) ? w_ih : (gate == 2) ? w_fh : w_oh;
        v = wh[i * 512 + k];
    } else if (k < 522) {
        const float* wx = (gate == 0) ? w_gx : (gate == 1) ? w_ix : (gate == 2) ? w_fx : w_ox;
        v = wx[i * 10 + (k - 512)];
    }
    unsigned short hi = f2bf(v);
    unsigned short lo = f2bf(v - bf2f(hi));
    Whi[idx] = hi;
    Wlo[idx] = lo;
}

// ---------- prep: x -> Xhi/Xlo [t][b][32] ----------
__global__ void k_prep_x(const float* __restrict__ x,
                         unsigned short* __restrict__ Xhi, unsigned short* __restrict__ Xlo) {
    int idx = blockIdx.x * 256 + threadIdx.x;
    if (idx >= Tdim * Bdim * 32) return;
    int j = idx & 31;
    int b = (idx >> 5) & 255;
    int t = idx >> 13;
    float v = 0.f;
    if (j < 10) v = x[(b * Tdim + t) * 10 + j];
    unsigned short hi = f2bf(v);
    unsigned short lo = f2bf(v - bf2f(hi));
    Xhi[idx] = hi;
    Xlo[idx] = lo;
}

__global__ void k_zero(float* __restrict__ p) {
    p[blockIdx.x * 256 + threadIdx.x] = 0.f;
}

// ---------- persistent LSTM ----------
// 256 WGs x 512 thr. WG: 32 stacked rows x 64 cols. Wave (wm,wn): rows
// wm*16..+15, cols wn*16..+15. Lane: cell (i0 = rg*8+wm*4+q, colc).
// h layout: Hc[(ct*64+rg)*512 + c_local*8 + i0%8] -> 1KB/WG contiguous.
__global__ __launch_bounds__(512, 1) void k_persist(
    const unsigned short* __restrict__ Whi, const unsigned short* __restrict__ Wlo,
    const unsigned short* __restrict__ Xhi, const unsigned short* __restrict__ Xlo,
    unsigned short* H0c, unsigned short* H1c,
    float* __restrict__ Hf32,
    const float* __restrict__ bg, const float* __restrict__ bi,
    const float* __restrict__ bf_, const float* __restrict__ bo,
    unsigned* flags) {
    extern __shared__ unsigned short lds[];
    unsigned short* Lhi = lds;                       // [32][LROW]
    unsigned short* Llo = lds + 32 * LROW;           // [32][LROW]
    unsigned short* Pp  = lds + 32 * LROW * 2;       // [64][PROW] panel
    unsigned short* Ho  = Pp + 64 * PROW;            // [64][8] h-out bounce

    const int bid = blockIdx.x;
    const int rg  = bid >> 2;                  // row-group id (0..63)
    const int m0  = rg * 32;                   // stacked-row tile base
    const int ct  = bid & 3;                   // column-group id (0..3)
    const int bn0 = ct * 64;
    const int tid = threadIdx.x;
    const int lane = tid & 63;
    const int w  = tid >> 6;                   // wave id 0..7
    const int wm = w >> 2;                     // row position (0..1)
    const int wn = w & 3;                      // col position (0..3)
    const int lr = lane & 15, q = lane >> 4;

    // flags: one 64B line per WG: index (ct*64+rg)*16 uints
    unsigned* myflag = flags + (((ct << 6) + rg) << 4);
    const unsigned* pollp = flags + (((ct << 6) + lane) << 4);  // lane l -> WG (ct,l)

    // panel staging role: thread (cl = tid>>3 col 0..63, e = tid&7)
    const int cl = tid >> 3;
    const int e  = tid & 7;

    // one-time weight staging global -> LDS (32 rows x 544)
    for (int it = tid; it < 32 * 68; it += 512) {
        int r = it / 68, c8 = (it % 68) * 8;
        *(bf16x8*)&Lhi[r * LROW + c8] = ld8(Whi + (size_t)(m0 + r) * Kpad + c8);
        *(bf16x8*)&Llo[r * LROW + c8] = ld8(Wlo + (size_t)(m0 + r) * Kpad + c8);
    }
    __syncthreads();

    const int kq = q * 8;
    const int colc = bn0 + wn * 16 + lr;       // this lane's column
    const int i0 = rg * 8 + wm * 4 + q;        // this lane's h-row
    const int i08 = wm * 4 + q;                // i0 % 8
    const int c_local = wn * 16 + lr;          // col within WG (0..63)

    float c0 = 0.f;
    const f32x4 binit = { bg[i0], bi[i0], bf_[i0], bo[i0] };

    const unsigned short* Ah = &Lhi[(wm * 16 + lr) * LROW + kq];
    const unsigned short* Al = &Llo[(wm * 16 + lr) * LROW + kq];
    const unsigned short* Bl = &Pp[c_local * PROW + kq];

    // global h block base (compact layout): this WG's 1KB block
    const size_t myblk = ((size_t)ct * 64 + rg) * 512;

    for (int t = 0; t < Tdim; ++t) {
        const unsigned short* Rh = (t & 1) ? H1c : H0c;   // holds h(t-1)
        unsigned short* Whc = (t & 1) ? H0c : H1c;        // receives h(t)
        // ---- 1. gate: all 64 producer WGs of this ct posted flag >= t ----
        poll64(pollp, (unsigned)t);

        // ---- 2. staging: 8 chunks of 16B per thread (batched), + x frags ----
        u64 s[8][2];
#pragma unroll
        for (int j = 0; j < 8; ++j) {
            const int rgp = j * 8 + e;
            const u64* sp = (const u64*)(Rh + (((size_t)ct * 64 + rgp) * 512 + cl * 8));
            s[j][0] = ldA(sp);
            s[j][1] = ldA(sp + 1);
        }
        const unsigned short* xb  = Xhi + ((size_t)t * Bdim + colc) * 32 + kq;
        const unsigned short* xbl = Xlo + ((size_t)t * Bdim + colc) * 32 + kq;
        bf16x8 xh = ld8(xb), xl = ld8(xbl);
        // panel write: position i = rgp*8..+7 of column cl
#pragma unroll
        for (int j = 0; j < 8; ++j) {
            const int rgp = j * 8 + e;
            *(bf16x8*)&Pp[cl * PROW + rgp * 8] = pack2(s[j][0], s[j][1]);
        }
        __syncthreads();                       // S1: panel ready

        // ---- 3. MFMA: 16 kb x (hi+lo) + x tail, single accumulator ----
        f32x4 acc = binit;
#pragma unroll
        for (int kb = 0; kb < 16; ++kb) {
            const int k = kb * 32;
            bf16x8 ah = ld8(Ah + k), al = ld8(Al + k);
            bf16x8 bh = ld8(Bl + k);
            acc = mfma16(ah, bh, acc);
            acc = mfma16(al, bh, acc);
        }
        {   // x tail
            bf16x8 ah = ld8(Ah + 512), al = ld8(Al + 512);
            acc = mfma16(ah, xh, acc);
            acc = mfma16(ah, xl, acc);
            acc = mfma16(al, xh, acc);
        }

        // ---- 4. epilogue: cell (i0, colc) -> Ho bounce ----
        {
            float g = tanh_fast(acc[0]), ii = sigm(acc[1]);
            float f = sigm(acc[2]),      o  = sigm(acc[3]);
            c0 = g * ii + c0 * f;
            float h = tanh_fast(c0) * o;
            Ho[c_local * 8 + i08] = f2bf(h);
            if (t == Tdim - 1) Hf32[(size_t)colc * Hdim + i0] = h;
        }
        __syncthreads();                       // S2: Ho complete; panel consumed

        // ---- 5. coalesced write-through store: 1KB/WG, threads 0-255 ----
        if (tid < 256)
            stH32((unsigned*)(Whc + myblk) + tid, ((const unsigned*)Ho)[tid]);
        __syncthreads();                       // S3: stores drained (per-wave vmcnt)

        // ---- 6. post flag(t+1) ----
        if (tid == 0)
            __hip_atomic_store(myflag, (unsigned)(t + 1),
                               __ATOMIC_RELAXED, __HIP_MEMORY_SCOPE_AGENT);
    }
}

// ---------- output: logits + softmax, one block per batch element ----------
__global__ __launch_bounds__(64) void k_out(
    const float* __restrict__ Hf32, const float* __restrict__ w_out,
    const float* __restrict__ b_out, float* __restrict__ out) {
    int b = blockIdx.x;
    int lane = threadIdx.x;
    const f32x4* h4 = (const f32x4*)(Hf32 + (size_t)b * 512);
    f32x4 h0 = h4[lane * 2], h1 = h4[lane * 2 + 1];
    float acc[10];
#pragma unroll
    for (int c = 0; c < 10; ++c) {
        const f32x4* w4 = (const f32x4*)(w_out + c * 512);
        f32x4 w0 = w4[lane * 2], w1 = w4[lane * 2 + 1];
        acc[c] = h0[0]*w0[0] + h0[1]*w0[1] + h0[2]*w0[2] + h0[3]*w0[3]
               + h1[0]*w1[0] + h1[1]*w1[1] + h1[2]*w1[2] + h1[3]*w1[3];
    }
#pragma unroll
    for (int s = 32; s >= 1; s >>= 1)
#pragma unroll
        for (int c = 0; c < 10; ++c) acc[c] += __shfl_xor(acc[c], s, 64);
    if (lane == 0) {
        float logit[10];
#pragma unroll
        for (int c = 0; c < 10; ++c) logit[c] = acc[c] + b_out[c];
        float m = logit[0];
#pragma unroll
        for (int c = 1; c < 10; ++c) m = fmaxf(m, logit[c]);
        float e[10], sum = 0.f;
#pragma unroll
        for (int c = 0; c < 10; ++c) { e[c] = __expf(logit[c] - m); sum += e[c]; }
        float inv = 1.f / sum;
#pragma unroll
        for (int c = 0; c < 10; ++c) out[b * 10 + c] = e[c] * inv;
    }
}

extern "C" void kernel_launch(void* const* d_in, const int* in_sizes, int n_in,
                              void* d_out, int out_size, void* d_ws, size_t ws_size,
                              hipStream_t stream) {
    const float* x    = (const float*)d_in[0];
    const float* w_gx = (const float*)d_in[1];
    const float* w_gh = (const float*)d_in[2];
    const float* b_g  = (const float*)d_in[3];
    const float* w_ix = (const float*)d_in[4];
    const float* w_ih = (const float*)d_in[5];
    const float* b_i  = (const float*)d_in[6];
    const float* w_fx = (const float*)d_in[7];
    const float* w_fh = (const float*)d_in[8];
    const float* b_f  = (const float*)d_in[9];
    const float* w_ox = (const float*)d_in[10];
    const float* w_oh = (const float*)d_in[11];
    const float* b_o  = (const float*)d_in[12];
    const float* w_out = (const float*)d_in[13];
    const float* b_out = (const float*)d_in[14];
    float* out = (float*)d_out;

    char* ws = (char*)d_ws;
    size_t off = 0;
    auto alloc = [&](size_t bytes) { void* p = ws + off; off += (bytes + 255) & ~255ull; return p; };
    // flags (16KB) | H0c contiguous -> one zeroing kernel
    unsigned*       flags = (unsigned*)alloc(16384);      // 256 WG-flags, 64B apart
    unsigned short* H0c   = (unsigned short*)alloc((size_t)Bdim * 512 * 2);
    unsigned short* H1c   = (unsigned short*)alloc((size_t)Bdim * 512 * 2);
    float*          Hf32  = (float*)alloc((size_t)Bdim * 512 * 4);
    unsigned short* Whi   = (unsigned short*)alloc(2048ull * Kpad * 2);
    unsigned short* Wlo   = (unsigned short*)alloc(2048ull * Kpad * 2);
    unsigned short* Xhi   = (unsigned short*)alloc((size_t)Tdim * Bdim * 32 * 2);
    unsigned short* Xlo   = (unsigned short*)alloc((size_t)Tdim * Bdim * 32 * 2);
    (void)ws_size; (void)in_sizes; (void)n_in; (void)out_size;

    k_prep_w<<<(2048 * Kpad + 255) / 256, 256, 0, stream>>>(
        w_gh, w_ih, w_fh, w_oh, w_gx, w_ix, w_fx, w_ox, Whi, Wlo);
    k_prep_x<<<(Tdim * Bdim * 32 + 255) / 256, 256, 0, stream>>>(x, Xhi, Xlo);
    // zero flags(16KB)+H0c(256KB): 278,528 B = 69,632 floats = 272 blocks
    k_zero<<<272, 256, 0, stream>>>((float*)flags);

    hipFuncSetAttribute((const void*)k_persist,
                        hipFuncAttributeMaxDynamicSharedMemorySize, LDS_BYTES);
    k_persist<<<dim3(256), dim3(512), LDS_BYTES, stream>>>(
        Whi, Wlo, Xhi, Xlo, H0c, H1c,
        Hf32, b_g, b_i, b_f, b_o, flags);

    k_out<<<256, 64, 0, stream>>>(Hf32, w_out, b_out, out);
}